// Round 5
// baseline (6803.249 us; speedup 1.0000x reference)
//
#include <hip/hip_runtime.h>

typedef __bf16 bhalf;
typedef __bf16 bh8_t __attribute__((ext_vector_type(8)));
typedef float f4_t __attribute__((ext_vector_type(4)));

#define MFMA16(A, B, C) __builtin_amdgcn_mfma_f32_16x16x32_bf16((A), (B), (C), 0, 0, 0)

// Problem sizes: B=32768, D_IN=128, H=1024, N_FLUX=512, N_MET=256, N_IN=128
// M = 64 rows/block, 512 blocks, 1024 threads = 16 waves.
// Wave (mw=w>>3, nw=w&7): m-tiles {2mw,2mw+1}, loop n-tiles {4nw..4nw+3}.
// Per-thread persistent state: Vreg[2][4]+Dreg[2][4] = 64 f32; peak live ~110
// fits the compiler's 128-VGPR target -> no spill (rounds 2-4: ~1.5-2 GB/dispatch
// scratch traffic because 230-reg live set was force-fit into 128 VGPRs;
// launch_bounds could not raise the cap).

// Workspace layout (bf16 elements):
//  W1t  [1024][128]  = W1^T
//  W2t  [512][1024]  = W2^T
//  SPin [384][512]   = rows 0-255: S, rows 256-383: Pin
//  St   [512][256]   = S^T * 2/256
//  Pt   [512][128]   = Pin^T * 2/128
#define OFF_W1T  0
#define OFF_W2T  (OFF_W1T + 1024 * 128)
#define OFF_SPIN (OFF_W2T + 512 * 1024)
#define OFF_ST   (OFF_SPIN + 384 * 512)
#define OFF_PT   (OFF_ST + 512 * 256)

__global__ __launch_bounds__(256) void amn_prep(
    const float* __restrict__ W1, const float* __restrict__ W2,
    const float* __restrict__ S, const float* __restrict__ Pin,
    bhalf* __restrict__ ws) {
  unsigned i = blockIdx.x * 256u + threadIdx.x;
  if (i < 131072u) {                   // W1t[n][k] = W1[k][n]
    unsigned n = i >> 7, k = i & 127u;
    ws[OFF_W1T + i] = (bhalf)W1[k * 1024u + n];
  } else if (i < 655360u) {            // W2t[n][k] = W2[k][n]
    unsigned j = i - 131072u;
    unsigned n = j >> 10, k = j & 1023u;
    ws[OFF_W2T + j] = (bhalf)W2[k * 512u + n];
  } else if (i < 851968u) {            // SPin: [S ; Pin] row-major
    unsigned j = i - 655360u;
    unsigned r = j >> 9, k = j & 511u;
    float v = (r < 256u) ? S[r * 512u + k] : Pin[(r - 256u) * 512u + k];
    ws[OFF_SPIN + j] = (bhalf)v;
  } else if (i < 983040u) {            // St[n][k] = S[k][n] * 2/256
    unsigned j = i - 851968u;
    unsigned n = j >> 8, k = j & 255u;
    ws[OFF_ST + j] = (bhalf)(S[k * 512u + n] * 0.0078125f);
  } else if (i < 1048576u) {           // Pt[n][k] = Pin[k][n] * 2/128
    unsigned j = i - 983040u;
    unsigned n = j >> 7, k = j & 127u;
    ws[OFF_PT + j] = (bhalf)(Pin[k * 512u + n] * 0.015625f);
  }
}

__device__ inline bh8_t cvt8(f4_t f0, f4_t f1) {
  bh8_t r;
  r[0] = (bhalf)f0[0]; r[1] = (bhalf)f0[1]; r[2] = (bhalf)f0[2]; r[3] = (bhalf)f0[3];
  r[4] = (bhalf)f1[0]; r[5] = (bhalf)f1[1]; r[6] = (bhalf)f1[2]; r[7] = (bhalf)f1[3];
  return r;
}

// LDS map (bf16 element offsets; total 75264 elem = 150,528 B):
//   V_lds  [64][520]  @ 0       (66,560 B)
//   T_lds  [64][264]  @ 33280   (33,792 B)
//   R_lds  [64][136]  @ 50176   (17,408 B)
//   Vin    [64][128]  @ 58880   (f32, 32,768 B)
//   hid    [64][1032] @ 0       (132,096 B, MLP phase only, aliases all of the above)
#define SM_TOTAL 75264
#define SMV   0
#define SMT   33280
#define SMR   50176
#define SMVIN 58880

__global__ __launch_bounds__(1024) void amn_main(
    const float* __restrict__ input, const float* __restrict__ Vin,
    const float* __restrict__ b1, const float* __restrict__ b2,
    const int* __restrict__ niter_p,
    const bhalf* __restrict__ ws, float* __restrict__ out) {

  const unsigned tid = threadIdx.x;
  const unsigned w  = tid >> 6;    // wave 0..15
  const unsigned mw = w >> 3;      // 0..1  -> m-tiles {2mw, 2mw+1}
  const unsigned nw = w & 7u;      // 0..7
  const unsigned l  = tid & 63u;
  const unsigned lq = l >> 4;      // 0..3
  const unsigned lr = l & 15u;     // 0..15
  const unsigned row0 = blockIdx.x * 64u;

  const bhalf* W1t  = ws + OFF_W1T;
  const bhalf* W2t  = ws + OFF_W2T;
  const bhalf* SPin = ws + OFF_SPIN;
  const bhalf* St   = ws + OFF_ST;
  const bhalf* Pt   = ws + OFF_PT;

  __shared__ __align__(16) bhalf smem[SM_TOTAL];
  bhalf* V_lds  = smem + SMV;
  bhalf* T_lds  = smem + SMT;
  bhalf* R_lds  = smem + SMR;
  float* Vin_lds = (float*)(smem + SMVIN);
  bhalf* hid_lds = smem;

  // ================= MLP phase 1: hidden = relu(input @ W1 + b1) =================
  // wave (mw,nw): m-tiles {2mw,2mw+1}, hidden n-tiles {8nw..8nw+7}
  {
    f4_t hacc[2][8];
#pragma unroll
    for (int mt = 0; mt < 2; ++mt)
#pragma unroll
      for (int t = 0; t < 8; ++t) hacc[mt][t] = (f4_t)0.f;

#pragma unroll
    for (int k = 0; k < 4; ++k) {   // K = 128
      bh8_t a[2];
#pragma unroll
      for (int mt = 0; mt < 2; ++mt) {
        const float* ap = input + (row0 + 16u * (2u * mw + mt) + lr) * 128u + k * 32 + lq * 8u;
        f4_t f0 = *(const f4_t*)ap;
        f4_t f1 = *(const f4_t*)(ap + 4);
        a[mt] = cvt8(f0, f1);
      }
#pragma unroll
      for (int t = 0; t < 8; ++t) {
        bh8_t b = *(const bh8_t*)(W1t + (16u * (8u * nw + t) + lr) * 128u + k * 32 + lq * 8u);
#pragma unroll
        for (int mt = 0; mt < 2; ++mt) hacc[mt][t] = MFMA16(a[mt], b, hacc[mt][t]);
      }
    }
#pragma unroll
    for (int t = 0; t < 8; ++t) {
      unsigned col = 16u * (8u * nw + t) + lr;
      float bias = b1[col];
#pragma unroll
      for (int mt = 0; mt < 2; ++mt)
#pragma unroll
        for (int r = 0; r < 4; ++r) {
          float v = fmaxf(hacc[mt][t][r] + bias, 0.f);
          hid_lds[(16u * (2u * mw + mt) + 4u * lq + r) * 1032u + col] = (bhalf)v;
        }
    }
  }
  __syncthreads();

  // ================= MLP phase 2: V0 = hidden @ W2 + b2 =================
  // wave (mw,nw): m-tiles {2mw,2mw+1}, V n-tiles {4nw..4nw+3}
  f4_t Vreg[2][4];
#pragma unroll
  for (int mt = 0; mt < 2; ++mt)
#pragma unroll
    for (int n = 0; n < 4; ++n) Vreg[mt][n] = (f4_t)0.f;

#pragma unroll
  for (int k = 0; k < 32; ++k) {  // K = 1024
    bh8_t a[2];
#pragma unroll
    for (int mt = 0; mt < 2; ++mt)
      a[mt] = *(const bh8_t*)(hid_lds + (16u * (2u * mw + mt) + lr) * 1032u + k * 32 + lq * 8u);
#pragma unroll
    for (int n = 0; n < 4; ++n) {
      bh8_t b = *(const bh8_t*)(W2t + (16u * (4u * nw + n) + lr) * 1024u + k * 32 + lq * 8u);
#pragma unroll
      for (int mt = 0; mt < 2; ++mt) Vreg[mt][n] = MFMA16(a[mt], b, Vreg[mt][n]);
    }
  }
#pragma unroll
  for (int n = 0; n < 4; ++n) {
    float bias = b2[16u * (4u * nw + n) + lr];
#pragma unroll
    for (int mt = 0; mt < 2; ++mt)
#pragma unroll
      for (int r = 0; r < 4; ++r) Vreg[mt][n][r] += bias;
  }
  __syncthreads();  // hid_lds dead from here; V/T/R/Vin regions become live

  // ---- load Vin (fp32) into LDS once: 64 rows x 128 cols ----
  {
    const float* vsrc = Vin + row0 * 128u;
#pragma unroll
    for (int p = 0; p < 2; ++p) {
      unsigned idx = (p * 1024u + tid) * 4u;       // 8192 floats, f4/thread/pass
      *(f4_t*)(Vin_lds + idx) = *(const f4_t*)(vsrc + idx);
    }
  }

  // ================= 30 momentum iterations =================
  f4_t Dreg[2][4];
#pragma unroll
  for (int mt = 0; mt < 2; ++mt)
#pragma unroll
    for (int n = 0; n < 4; ++n) Dreg[mt][n] = (f4_t)0.f;

  const int niter = niter_p[0];
  for (int it = 0; it < niter; ++it) {
    // ---- (i) stage V (bf16) to LDS ----
#pragma unroll
    for (int mt = 0; mt < 2; ++mt)
#pragma unroll
      for (int n = 0; n < 4; ++n) {
        unsigned col = 64u * nw + 16u * n + lr;
#pragma unroll
        for (int r = 0; r < 4; ++r)
          V_lds[(16u * (2u * mw + mt) + 4u * lq + r) * 520u + col] = (bhalf)Vreg[mt][n][r];
      }
    __syncthreads();

    // ---- (ii) [T|U] = V @ [S^T | Pin^T], K = 512 ----
    // wave (mw,nw): m-tiles {2mw,2mw+1}, TU n-tiles {3nw..3nw+2} of 24
    f4_t acc[2][3];
#pragma unroll
    for (int mt = 0; mt < 2; ++mt)
#pragma unroll
      for (int tt = 0; tt < 3; ++tt) acc[mt][tt] = (f4_t)0.f;

#pragma unroll
    for (int k = 0; k < 16; ++k) {
      bh8_t a[2];
#pragma unroll
      for (int mt = 0; mt < 2; ++mt)
        a[mt] = *(const bh8_t*)(V_lds + (16u * (2u * mw + mt) + lr) * 520u + k * 32 + lq * 8u);
#pragma unroll
      for (int tt = 0; tt < 3; ++tt) {
        bh8_t b = *(const bh8_t*)(SPin + (16u * (3u * nw + tt) + lr) * 512u + k * 32 + lq * 8u);
#pragma unroll
        for (int mt = 0; mt < 2; ++mt) acc[mt][tt] = MFMA16(a[mt], b, acc[mt][tt]);
      }
    }
    // store T (bf16) / relu(U - Vin) (bf16)
#pragma unroll
    for (int tt = 0; tt < 3; ++tt) {
      int t = 3 * (int)nw + tt;
      if (t < 16) {
#pragma unroll
        for (int mt = 0; mt < 2; ++mt)
#pragma unroll
          for (int r = 0; r < 4; ++r)
            T_lds[(16u * (2u * mw + mt) + 4u * lq + r) * 264u + 16u * t + lr] =
                (bhalf)acc[mt][tt][r];
      } else {
        int u = t - 16;
#pragma unroll
        for (int mt = 0; mt < 2; ++mt)
#pragma unroll
          for (int r = 0; r < 4; ++r) {
            float vin = Vin_lds[(16u * (2u * mw + mt) + 4u * lq + r) * 128u + 16u * u + lr];
            R_lds[(16u * (2u * mw + mt) + 4u * lq + r) * 136u + 16u * u + lr] =
                (bhalf)fmaxf(acc[mt][tt][r] - vin, 0.f);
          }
      }
    }
    __syncthreads();

    // ---- (iii) per n-tile: dacc = T @ St + R @ Pt, then update V/diff ----
#pragma unroll
    for (int n = 0; n < 4; ++n) {
      f4_t dacc[2];
      dacc[0] = (f4_t)0.f;
      dacc[1] = (f4_t)0.f;

#pragma unroll
      for (int k = 0; k < 8; ++k) {   // K = 256 (T @ St)
        bh8_t b = *(const bh8_t*)(St + (16u * (4u * nw + n) + lr) * 256u + k * 32 + lq * 8u);
#pragma unroll
        for (int mt = 0; mt < 2; ++mt) {
          bh8_t a = *(const bh8_t*)(T_lds + (16u * (2u * mw + mt) + lr) * 264u + k * 32 + lq * 8u);
          dacc[mt] = MFMA16(a, b, dacc[mt]);
        }
      }
#pragma unroll
      for (int k = 0; k < 4; ++k) {   // K = 128 (R @ Pt)
        bh8_t b = *(const bh8_t*)(Pt + (16u * (4u * nw + n) + lr) * 128u + k * 32 + lq * 8u);
#pragma unroll
        for (int mt = 0; mt < 2; ++mt) {
          bh8_t a = *(const bh8_t*)(R_lds + (16u * (2u * mw + mt) + lr) * 136u + k * 32 + lq * 8u);
          dacc[mt] = MFMA16(a, b, dacc[mt]);
        }
      }

      // update: dV += min(V,0)*2/512; diff = 0.9 diff - 0.01 dV; V += diff
#pragma unroll
      for (int mt = 0; mt < 2; ++mt)
#pragma unroll
        for (int r = 0; r < 4; ++r) {
          float dv = dacc[mt][r] + fminf(Vreg[mt][n][r], 0.f) * 0.00390625f;
          float d = 0.9f * Dreg[mt][n][r] - 0.01f * dv;
          Dreg[mt][n][r] = d;
          Vreg[mt][n][r] += d;
        }
    }
  }

  // ---- write final V (fp32) ----
#pragma unroll
  for (int mt = 0; mt < 2; ++mt)
#pragma unroll
    for (int n = 0; n < 4; ++n) {
      unsigned col = 64u * nw + 16u * n + lr;
#pragma unroll
      for (int r = 0; r < 4; ++r)
        out[(row0 + 16u * (2u * mw + mt) + 4u * lq + r) * 512u + col] = Vreg[mt][n][r];
    }
}

extern "C" void kernel_launch(void* const* d_in, const int* in_sizes, int n_in,
                              void* d_out, int out_size, void* d_ws, size_t ws_size,
                              hipStream_t stream) {
  const float* input = (const float*)d_in[0];
  // d_in[1] = Vref (unused by reference)
  const float* Vin = (const float*)d_in[2];
  const float* W1  = (const float*)d_in[3];
  const float* b1  = (const float*)d_in[4];
  const float* W2  = (const float*)d_in[5];
  const float* b2  = (const float*)d_in[6];
  const float* S   = (const float*)d_in[7];
  const float* Pin = (const float*)d_in[8];
  const int* nit   = (const int*)d_in[9];
  bhalf* ws  = (bhalf*)d_ws;
  float* out = (float*)d_out;

  amn_prep<<<4096, 256, 0, stream>>>(W1, W2, S, Pin, ws);
  amn_main<<<512, 1024, 0, stream>>>(input, Vin, b1, b2, nit, ws, out);
}

// Round 6
// 4304.273 us; speedup vs baseline: 1.5806x; 1.5806x over previous
//
#include <hip/hip_runtime.h>

typedef __bf16 bhalf;
typedef __bf16 bh8_t __attribute__((ext_vector_type(8)));
typedef float f4_t __attribute__((ext_vector_type(4)));

#define MFMA16(A, B, C) __builtin_amdgcn_mfma_f32_16x16x32_bf16((A), (B), (C), 0, 0, 0)

// Problem sizes: B=32768, D_IN=128, H=1024, N_FLUX=512, N_MET=256, N_IN=128
//
// KEY LESSON (rounds 2-5): hipcc allocates VGPRs for 2 blocks/CU regardless of
// LDS or __launch_bounds__: budget = 256*(256/block_threads). 512t->128, 1024t->64
// (both spilled 1.5-2.5 GB/dispatch and thrashed L2). 256-thread blocks get a
// 256-VGPR budget (m97 precedent: 164 allocated).
//
// This round: M=32 rows/block, 256 threads = 4 waves, 1024 blocks.
// Wave w owns n-cols [128w,128w+128) x both m-tiles. Persistent state/thread:
// Vreg[2][8]+Dreg[2][8] = 128 f32; peak live ~185 < 256 -> zero spill.
// LDS 75 KB -> 2 blocks/CU (heuristic's assumption finally true).

// Workspace layout (bf16 elements):
#define OFF_W1T  0
#define OFF_W2T  (OFF_W1T + 1024 * 128)
#define OFF_SPIN (OFF_W2T + 512 * 1024)
#define OFF_ST   (OFF_SPIN + 384 * 512)
#define OFF_PT   (OFF_ST + 512 * 256)

__global__ __launch_bounds__(256) void amn_prep(
    const float* __restrict__ W1, const float* __restrict__ W2,
    const float* __restrict__ S, const float* __restrict__ Pin,
    bhalf* __restrict__ ws) {
  unsigned i = blockIdx.x * 256u + threadIdx.x;
  if (i < 131072u) {                   // W1t[n][k] = W1[k][n]
    unsigned n = i >> 7, k = i & 127u;
    ws[OFF_W1T + i] = (bhalf)W1[k * 1024u + n];
  } else if (i < 655360u) {            // W2t[n][k] = W2[k][n]
    unsigned j = i - 131072u;
    unsigned n = j >> 10, k = j & 1023u;
    ws[OFF_W2T + j] = (bhalf)W2[k * 512u + n];
  } else if (i < 851968u) {            // SPin: [S ; Pin] row-major
    unsigned j = i - 655360u;
    unsigned r = j >> 9, k = j & 511u;
    float v = (r < 256u) ? S[r * 512u + k] : Pin[(r - 256u) * 512u + k];
    ws[OFF_SPIN + j] = (bhalf)v;
  } else if (i < 983040u) {            // St[n][k] = S[k][n] * 2/256
    unsigned j = i - 851968u;
    unsigned n = j >> 8, k = j & 255u;
    ws[OFF_ST + j] = (bhalf)(S[k * 512u + n] * 0.0078125f);
  } else if (i < 1048576u) {           // Pt[n][k] = Pin[k][n] * 2/128
    unsigned j = i - 983040u;
    unsigned n = j >> 7, k = j & 127u;
    ws[OFF_PT + j] = (bhalf)(Pin[k * 512u + n] * 0.015625f);
  }
}

__device__ inline bh8_t cvt8(f4_t f0, f4_t f1) {
  bh8_t r;
  r[0] = (bhalf)f0[0]; r[1] = (bhalf)f0[1]; r[2] = (bhalf)f0[2]; r[3] = (bhalf)f0[3];
  r[4] = (bhalf)f1[0]; r[5] = (bhalf)f1[1]; r[6] = (bhalf)f1[2]; r[7] = (bhalf)f1[3];
  return r;
}

// LDS map (bf16 element offsets; total 37632 elem = 75,264 B -> 2 blocks/CU):
//   V_lds  [32][520]  @ 0      (33,280 B)
//   T_lds  [32][264]  @ 16640  (16,896 B)
//   R_lds  [32][136]  @ 25088  ( 8,704 B)
//   Vin    [32][128]  @ 29440  (f32, 16,384 B) -- loaded AFTER MLP (aliases hid tail)
//   hid    [32][1032] @ 0      (66,048 B, MLP phase only, aliases all of the above)
#define SM_TOTAL 37632
#define SMV   0
#define SMT   16640
#define SMR   25088
#define SMVIN 29440

__global__ __launch_bounds__(256) void amn_main(
    const float* __restrict__ input, const float* __restrict__ Vin,
    const float* __restrict__ b1, const float* __restrict__ b2,
    const int* __restrict__ niter_p,
    const bhalf* __restrict__ ws, float* __restrict__ out) {

  const unsigned tid = threadIdx.x;
  const unsigned w  = tid >> 6;    // wave 0..3
  const unsigned l  = tid & 63u;
  const unsigned lq = l >> 4;      // 0..3
  const unsigned lr = l & 15u;     // 0..15
  const unsigned row0 = blockIdx.x * 32u;

  const bhalf* W1t  = ws + OFF_W1T;
  const bhalf* W2t  = ws + OFF_W2T;
  const bhalf* SPin = ws + OFF_SPIN;
  const bhalf* St   = ws + OFF_ST;
  const bhalf* Pt   = ws + OFF_PT;

  __shared__ __align__(16) bhalf smem[SM_TOTAL];
  bhalf* V_lds  = smem + SMV;
  bhalf* T_lds  = smem + SMT;
  bhalf* R_lds  = smem + SMR;
  float* Vin_lds = (float*)(smem + SMVIN);
  bhalf* hid_lds = smem;

  // ================= MLP phase 1: hidden = relu(input @ W1 + b1) =================
  // wave w owns hidden t-tiles {16w..16w+15}, chunked by 8 (hacc transient 64 regs)
#pragma unroll
  for (int tc = 0; tc < 2; ++tc) {
    f4_t hacc[2][8];
#pragma unroll
    for (int mt = 0; mt < 2; ++mt)
#pragma unroll
      for (int t = 0; t < 8; ++t) hacc[mt][t] = (f4_t)0.f;

#pragma unroll
    for (int k = 0; k < 4; ++k) {   // K = 128
      bh8_t a[2];
#pragma unroll
      for (int mt = 0; mt < 2; ++mt) {
        const float* ap = input + (row0 + 16u * mt + lr) * 128u + k * 32 + lq * 8u;
        f4_t f0 = *(const f4_t*)ap;
        f4_t f1 = *(const f4_t*)(ap + 4);
        a[mt] = cvt8(f0, f1);
      }
#pragma unroll
      for (int t = 0; t < 8; ++t) {
        unsigned trow = 16u * (16u * w + 8u * tc + t) + lr;
        bh8_t b = *(const bh8_t*)(W1t + trow * 128u + k * 32 + lq * 8u);
#pragma unroll
        for (int mt = 0; mt < 2; ++mt) hacc[mt][t] = MFMA16(a[mt], b, hacc[mt][t]);
      }
    }
#pragma unroll
    for (int t = 0; t < 8; ++t) {
      unsigned col = 16u * (16u * w + 8u * tc + t) + lr;
      float bias = b1[col];
#pragma unroll
      for (int mt = 0; mt < 2; ++mt)
#pragma unroll
        for (int r = 0; r < 4; ++r) {
          float v = fmaxf(hacc[mt][t][r] + bias, 0.f);
          hid_lds[(16u * mt + 4u * lq + r) * 1032u + col] = (bhalf)v;
        }
    }
  }
  __syncthreads();

  // ================= MLP phase 2: V0 = hidden @ W2 + b2 =================
  // wave w owns V n-tiles {8w..8w+7}
  f4_t Vreg[2][8];
#pragma unroll
  for (int mt = 0; mt < 2; ++mt)
#pragma unroll
    for (int n = 0; n < 8; ++n) Vreg[mt][n] = (f4_t)0.f;

#pragma unroll
  for (int k = 0; k < 32; ++k) {  // K = 1024
    bh8_t a[2];
#pragma unroll
    for (int mt = 0; mt < 2; ++mt)
      a[mt] = *(const bh8_t*)(hid_lds + (16u * mt + lr) * 1032u + k * 32 + lq * 8u);
#pragma unroll
    for (int n = 0; n < 8; ++n) {
      bh8_t b = *(const bh8_t*)(W2t + (16u * (8u * w + n) + lr) * 1024u + k * 32 + lq * 8u);
#pragma unroll
      for (int mt = 0; mt < 2; ++mt) Vreg[mt][n] = MFMA16(a[mt], b, Vreg[mt][n]);
    }
  }
#pragma unroll
  for (int n = 0; n < 8; ++n) {
    float bias = b2[16u * (8u * w + n) + lr];
#pragma unroll
    for (int mt = 0; mt < 2; ++mt)
#pragma unroll
      for (int r = 0; r < 4; ++r) Vreg[mt][n][r] += bias;
  }
  __syncthreads();  // hid_lds dead from here

  // ---- load Vin (fp32) into LDS once: 32 rows x 128 cols = 4096 floats ----
  {
    const float* vsrc = Vin + row0 * 128u;
#pragma unroll
    for (int p = 0; p < 4; ++p) {
      unsigned idx = (p * 256u + tid) * 4u;
      *(f4_t*)(Vin_lds + idx) = *(const f4_t*)(vsrc + idx);
    }
  }

  // ================= 30 momentum iterations =================
  f4_t Dreg[2][8];
#pragma unroll
  for (int mt = 0; mt < 2; ++mt)
#pragma unroll
    for (int n = 0; n < 8; ++n) Dreg[mt][n] = (f4_t)0.f;

  const int niter = niter_p[0];
  for (int it = 0; it < niter; ++it) {
    // ---- (i) stage V (bf16) to LDS ----
#pragma unroll
    for (int mt = 0; mt < 2; ++mt)
#pragma unroll
      for (int n = 0; n < 8; ++n) {
        unsigned col = 16u * (8u * w + n) + lr;
#pragma unroll
        for (int r = 0; r < 4; ++r)
          V_lds[(16u * mt + 4u * lq + r) * 520u + col] = (bhalf)Vreg[mt][n][r];
      }
    __syncthreads();

    // ---- (ii) [T|U] = V @ [S^T | Pin^T], K = 512 ----
    // wave w owns TU tiles {6w..6w+5} of 24 (0-15 = T, 16-23 = U), chunked by 3
#pragma unroll
    for (int tc = 0; tc < 2; ++tc) {
      f4_t acc[2][3];
#pragma unroll
      for (int mt = 0; mt < 2; ++mt)
#pragma unroll
        for (int tt = 0; tt < 3; ++tt) acc[mt][tt] = (f4_t)0.f;

#pragma unroll
      for (int k = 0; k < 16; ++k) {
        bh8_t a[2];
#pragma unroll
        for (int mt = 0; mt < 2; ++mt)
          a[mt] = *(const bh8_t*)(V_lds + (16u * mt + lr) * 520u + k * 32 + lq * 8u);
#pragma unroll
        for (int tt = 0; tt < 3; ++tt) {
          unsigned t = 6u * w + 3u * tc + tt;
          bh8_t b = *(const bh8_t*)(SPin + (16u * t + lr) * 512u + k * 32 + lq * 8u);
#pragma unroll
          for (int mt = 0; mt < 2; ++mt) acc[mt][tt] = MFMA16(a[mt], b, acc[mt][tt]);
        }
      }
      // store T (bf16) / relu(U - Vin) (bf16)
#pragma unroll
      for (int tt = 0; tt < 3; ++tt) {
        int t = 6 * (int)w + 3 * tc + tt;
        if (t < 16) {
#pragma unroll
          for (int mt = 0; mt < 2; ++mt)
#pragma unroll
            for (int r = 0; r < 4; ++r)
              T_lds[(16u * mt + 4u * lq + r) * 264u + 16u * t + lr] = (bhalf)acc[mt][tt][r];
        } else {
          int u = t - 16;
#pragma unroll
          for (int mt = 0; mt < 2; ++mt)
#pragma unroll
            for (int r = 0; r < 4; ++r) {
              float vin = Vin_lds[(16u * mt + 4u * lq + r) * 128u + 16u * u + lr];
              R_lds[(16u * mt + 4u * lq + r) * 136u + 16u * u + lr] =
                  (bhalf)fmaxf(acc[mt][tt][r] - vin, 0.f);
            }
        }
      }
    }
    __syncthreads();

    // ---- (iii) per n-tile: dacc = T @ St + R @ Pt, then update V/diff ----
#pragma unroll
    for (int n = 0; n < 8; ++n) {
      f4_t dacc[2];
      dacc[0] = (f4_t)0.f;
      dacc[1] = (f4_t)0.f;

#pragma unroll
      for (int k = 0; k < 8; ++k) {   // K = 256 (T @ St)
        bh8_t b = *(const bh8_t*)(St + (16u * (8u * w + n) + lr) * 256u + k * 32 + lq * 8u);
#pragma unroll
        for (int mt = 0; mt < 2; ++mt) {
          bh8_t a = *(const bh8_t*)(T_lds + (16u * mt + lr) * 264u + k * 32 + lq * 8u);
          dacc[mt] = MFMA16(a, b, dacc[mt]);
        }
      }
#pragma unroll
      for (int k = 0; k < 4; ++k) {   // K = 128 (R @ Pt)
        bh8_t b = *(const bh8_t*)(Pt + (16u * (8u * w + n) + lr) * 128u + k * 32 + lq * 8u);
#pragma unroll
        for (int mt = 0; mt < 2; ++mt) {
          bh8_t a = *(const bh8_t*)(R_lds + (16u * mt + lr) * 136u + k * 32 + lq * 8u);
          dacc[mt] = MFMA16(a, b, dacc[mt]);
        }
      }

      // update: dV += min(V,0)*2/512; diff = 0.9 diff - 0.01 dV; V += diff
#pragma unroll
      for (int mt = 0; mt < 2; ++mt)
#pragma unroll
        for (int r = 0; r < 4; ++r) {
          float dv = dacc[mt][r] + fminf(Vreg[mt][n][r], 0.f) * 0.00390625f;
          float d = 0.9f * Dreg[mt][n][r] - 0.01f * dv;
          Dreg[mt][n][r] = d;
          Vreg[mt][n][r] += d;
        }
    }
  }

  // ---- write final V (fp32) ----
#pragma unroll
  for (int mt = 0; mt < 2; ++mt)
#pragma unroll
    for (int n = 0; n < 8; ++n) {
      unsigned col = 16u * (8u * w + n) + lr;
#pragma unroll
      for (int r = 0; r < 4; ++r)
        out[(row0 + 16u * mt + 4u * lq + r) * 512u + col] = Vreg[mt][n][r];
    }
}

extern "C" void kernel_launch(void* const* d_in, const int* in_sizes, int n_in,
                              void* d_out, int out_size, void* d_ws, size_t ws_size,
                              hipStream_t stream) {
  const float* input = (const float*)d_in[0];
  // d_in[1] = Vref (unused by reference)
  const float* Vin = (const float*)d_in[2];
  const float* W1  = (const float*)d_in[3];
  const float* b1  = (const float*)d_in[4];
  const float* W2  = (const float*)d_in[5];
  const float* b2  = (const float*)d_in[6];
  const float* S   = (const float*)d_in[7];
  const float* Pin = (const float*)d_in[8];
  const int* nit   = (const int*)d_in[9];
  bhalf* ws  = (bhalf*)d_ws;
  float* out = (float*)d_out;

  amn_prep<<<4096, 256, 0, stream>>>(W1, W2, S, Pin, ws);
  amn_main<<<1024, 256, 0, stream>>>(input, Vin, b1, b2, nit, ws, out);
}

// Round 7
// 3544.060 us; speedup vs baseline: 1.9196x; 1.2145x over previous
//
#include <hip/hip_runtime.h>

typedef __bf16 bhalf;
typedef __bf16 bh8_t __attribute__((ext_vector_type(8)));
typedef float f4_t __attribute__((ext_vector_type(4)));

#define MFMA16(A, B, C) __builtin_amdgcn_mfma_f32_16x16x32_bf16((A), (B), (C), 0, 0, 0)

// Problem sizes: B=32768, D_IN=128, H=1024, N_FLUX=512, N_MET=256, N_IN=128
//
// ROUND 7 STRUCTURE (root cause from r2-r6: persistent V+diff in regs -> ~230
// live > any achievable budget -> spill scratch streamed ~2.6 MB/XCD/iter
// through L2, evicting the 768 KB B-operand set -> 35% L2 miss + latency-bound):
//  * V master (f32) lives in LDS [32][524] (stride 524: A-fragment ds_read_b128
//    bank-bases (12*lr+8*lq)%32 cover all eight 4-bank slots -> balanced).
//  * dV2 folded: G = S^T S * 2/256 precomputed (symmetric -> row-read = B^T read).
//  * Registers: diff[2][8] (64) + Vin (16) + transients -> ~160 live, no spill.
//  * LDS 75.8 KB -> 2 blocks/CU (8 waves/CU). 3 syncs/iter (V-update deferred
//    so phase-iii A-reads and fmin(V,0) see old V, per reference semantics).

// Workspace layout (bf16 elements):
//  W1t  [1024][128] = W1^T
//  W2t  [512][1024] = W2^T
//  Pinb [128][512]  = bf16(Pin)            (B for U = V @ Pin^T)
//  Pt   [512][128]  = Pin^T * 2/128        (B for dV3 = R @ Pin * 2/128)
//  G    [512][512]  = S^T S * 2/256        (B for dV2 = V @ G; symmetric)
#define OFF_W1T  0
#define OFF_W2T  (OFF_W1T + 1024 * 128)
#define OFF_PINB (OFF_W2T + 512 * 1024)
#define OFF_PT   (OFF_PINB + 128 * 512)
#define OFF_G    (OFF_PT + 512 * 128)
// total = 1,048,576 bf16 el = 2 MiB

__global__ __launch_bounds__(256) void amn_prep(
    const float* __restrict__ W1, const float* __restrict__ W2,
    const float* __restrict__ Pin, bhalf* __restrict__ ws) {
  unsigned i = blockIdx.x * 256u + threadIdx.x;
  if (i < 131072u) {                   // W1t[n][k] = W1[k][n]
    unsigned n = i >> 7, k = i & 127u;
    ws[OFF_W1T + i] = (bhalf)W1[k * 1024u + n];
  } else if (i < 655360u) {            // W2t[n][k] = W2[k][n]
    unsigned j = i - 131072u;
    unsigned n = j >> 10, k = j & 1023u;
    ws[OFF_W2T + j] = (bhalf)W2[k * 512u + n];
  } else if (i < 720896u) {            // Pinb = bf16(Pin), row-major direct
    unsigned j = i - 655360u;
    ws[OFF_PINB + j] = (bhalf)Pin[j];
  } else if (i < 786432u) {            // Pt[n][k] = Pin[k][n] * 2/128
    unsigned j = i - 720896u;
    unsigned n = j >> 7, k = j & 127u;
    ws[OFF_PT + j] = (bhalf)(Pin[k * 512u + n] * 0.015625f);
  }
}

// G[i][j] = (2/256) * sum_k S[k][i]*S[k][j]; block = 16x16 tile of G.
__global__ __launch_bounds__(256) void amn_gram(
    const float* __restrict__ S, bhalf* __restrict__ ws) {
  const unsigned bi = blockIdx.x >> 5, bj = blockIdx.x & 31u;
  __shared__ float SA[256][16];
  __shared__ float SB[256][16];
  const unsigned t = threadIdx.x;
#pragma unroll
  for (int p = 0; p < 16; ++p) {
    unsigned e = p * 256u + t;
    unsigned k = e >> 4, c = e & 15u;
    SA[k][c] = S[k * 512u + bi * 16u + c];
    SB[k][c] = S[k * 512u + bj * 16u + c];
  }
  __syncthreads();
  const unsigned ti = t >> 4, tj = t & 15u;
  float acc = 0.f;
#pragma unroll 8
  for (int k = 0; k < 256; ++k) acc += SA[k][ti] * SB[k][tj];
  ws[OFF_G + (bi * 16u + ti) * 512u + bj * 16u + tj] = (bhalf)(acc * 0.0078125f);
}

__device__ inline bh8_t cvt8(f4_t f0, f4_t f1) {
  bh8_t r;
  r[0] = (bhalf)f0[0]; r[1] = (bhalf)f0[1]; r[2] = (bhalf)f0[2]; r[3] = (bhalf)f0[3];
  r[4] = (bhalf)f1[0]; r[5] = (bhalf)f1[1]; r[6] = (bhalf)f1[2]; r[7] = (bhalf)f1[3];
  return r;
}

// LDS map (bytes; total 75,776 -> 2 blocks/CU):
//   Vf32 [32][524] f32 @ 0      (67,072 B)  V master, persists across iterations
//   R    [32][136] bf16 @ 67072 ( 8,704 B)  relu(U - Vin) staging
//   hid  [32][1032] bf16 @ 0    (66,048 B)  MLP phase only, aliases Vf32
#define SMEM_BYTES 75776
#define VSTRIDE 524u

__global__ __launch_bounds__(256) void amn_main(
    const float* __restrict__ input, const float* __restrict__ Vin,
    const float* __restrict__ b1, const float* __restrict__ b2,
    const int* __restrict__ niter_p,
    const bhalf* __restrict__ ws, float* __restrict__ out) {

  const unsigned tid = threadIdx.x;
  const unsigned w  = tid >> 6;    // wave 0..3
  const unsigned l  = tid & 63u;
  const unsigned lq = l >> 4;      // 0..3
  const unsigned lr = l & 15u;     // 0..15
  const unsigned row0 = blockIdx.x * 32u;

  const bhalf* W1t  = ws + OFF_W1T;
  const bhalf* W2t  = ws + OFF_W2T;
  const bhalf* Pinb = ws + OFF_PINB;
  const bhalf* Pt   = ws + OFF_PT;
  const bhalf* G    = ws + OFF_G;

  __shared__ __align__(16) unsigned char smem[SMEM_BYTES];
  float* Vf32    = (float*)smem;
  bhalf* R_lds   = (bhalf*)(smem + 67072);
  bhalf* hid_lds = (bhalf*)smem;

  // ================= MLP phase 1: hidden = relu(input @ W1 + b1) =================
  // wave w owns hidden tiles {16w..16w+15}, chunked by 8
#pragma unroll
  for (int tc = 0; tc < 2; ++tc) {
    f4_t hacc[2][8];
#pragma unroll
    for (int mt = 0; mt < 2; ++mt)
#pragma unroll
      for (int t = 0; t < 8; ++t) hacc[mt][t] = (f4_t)0.f;

#pragma unroll
    for (int k = 0; k < 4; ++k) {   // K = 128
      bh8_t a[2];
#pragma unroll
      for (int mt = 0; mt < 2; ++mt) {
        const float* ap = input + (row0 + 16u * mt + lr) * 128u + k * 32 + lq * 8u;
        f4_t f0 = *(const f4_t*)ap;
        f4_t f1 = *(const f4_t*)(ap + 4);
        a[mt] = cvt8(f0, f1);
      }
#pragma unroll
      for (int t = 0; t < 8; ++t) {
        unsigned trow = 16u * (16u * w + 8u * tc + t) + lr;
        bh8_t b = *(const bh8_t*)(W1t + trow * 128u + k * 32 + lq * 8u);
#pragma unroll
        for (int mt = 0; mt < 2; ++mt) hacc[mt][t] = MFMA16(a[mt], b, hacc[mt][t]);
      }
    }
#pragma unroll
    for (int t = 0; t < 8; ++t) {
      unsigned col = 16u * (16u * w + 8u * tc + t) + lr;
      float bias = b1[col];
#pragma unroll
      for (int mt = 0; mt < 2; ++mt)
#pragma unroll
        for (int r = 0; r < 4; ++r) {
          float v = fmaxf(hacc[mt][t][r] + bias, 0.f);
          hid_lds[(16u * mt + 4u * lq + r) * 1032u + col] = (bhalf)v;
        }
    }
  }
  __syncthreads();

  // ================= MLP phase 2: V0 = hidden @ W2 + b2 =================
  // wave w owns V n-tiles {8w..8w+7}
  f4_t Vacc[2][8];
#pragma unroll
  for (int mt = 0; mt < 2; ++mt)
#pragma unroll
    for (int n = 0; n < 8; ++n) Vacc[mt][n] = (f4_t)0.f;

#pragma unroll
  for (int k = 0; k < 32; ++k) {  // K = 1024
    bh8_t a[2];
#pragma unroll
    for (int mt = 0; mt < 2; ++mt)
      a[mt] = *(const bh8_t*)(hid_lds + (16u * mt + lr) * 1032u + k * 32 + lq * 8u);
#pragma unroll
    for (int n = 0; n < 8; ++n) {
      bh8_t b = *(const bh8_t*)(W2t + (16u * (8u * w + n) + lr) * 1024u + k * 32 + lq * 8u);
#pragma unroll
      for (int mt = 0; mt < 2; ++mt) Vacc[mt][n] = MFMA16(a[mt], b, Vacc[mt][n]);
    }
  }
  __syncthreads();  // all hid reads done; Vf32 region (aliased) may now be written

  // ---- write V0 (f32) into LDS master ----
#pragma unroll
  for (int mt = 0; mt < 2; ++mt)
#pragma unroll
    for (int n = 0; n < 8; ++n) {
      float bias = b2[16u * (8u * w + n) + lr];
#pragma unroll
      for (int r = 0; r < 4; ++r)
        Vf32[(16u * mt + 4u * lq + r) * VSTRIDE + 16u * (8u * w + n) + lr] =
            Vacc[mt][n][r] + bias;
    }

  // ---- Vin into registers (wave w owns u-tiles {2w, 2w+1}) ----
  float VinR[2][2][4];
#pragma unroll
  for (int j = 0; j < 2; ++j)
#pragma unroll
    for (int mt = 0; mt < 2; ++mt)
#pragma unroll
      for (int r = 0; r < 4; ++r)
        VinR[j][mt][r] =
            Vin[(row0 + 16u * mt + 4u * lq + r) * 128u + 16u * (2u * w + j) + lr];

  f4_t Dreg[2][8];
#pragma unroll
  for (int mt = 0; mt < 2; ++mt)
#pragma unroll
    for (int n = 0; n < 8; ++n) Dreg[mt][n] = (f4_t)0.f;

  __syncthreads();  // V0 fully written before first phase-ii reads

  // ================= 30 momentum iterations =================
  const int niter = niter_p[0];
  for (int it = 0; it < niter; ++it) {
    // ---- phase ii: U = V @ Pin^T (K=512); R = relu(U - Vin) -> LDS ----
    f4_t acc2[2][2];  // [u-tile j][mt]
#pragma unroll
    for (int j = 0; j < 2; ++j) { acc2[j][0] = (f4_t)0.f; acc2[j][1] = (f4_t)0.f; }

#pragma unroll
    for (int k = 0; k < 16; ++k) {
      bh8_t a[2];
#pragma unroll
      for (int mt = 0; mt < 2; ++mt) {
        const float* vp = Vf32 + (16u * mt + lr) * VSTRIDE + k * 32 + lq * 8u;
        a[mt] = cvt8(*(const f4_t*)vp, *(const f4_t*)(vp + 4));
      }
#pragma unroll
      for (int j = 0; j < 2; ++j) {
        bh8_t b = *(const bh8_t*)(Pinb + (16u * (2u * w + j) + lr) * 512u + k * 32 + lq * 8u);
#pragma unroll
        for (int mt = 0; mt < 2; ++mt) acc2[j][mt] = MFMA16(a[mt], b, acc2[j][mt]);
      }
    }
#pragma unroll
    for (int j = 0; j < 2; ++j)
#pragma unroll
      for (int mt = 0; mt < 2; ++mt)
#pragma unroll
        for (int r = 0; r < 4; ++r)
          R_lds[(16u * mt + 4u * lq + r) * 136u + 16u * (2u * w + j) + lr] =
              (bhalf)fmaxf(acc2[j][mt][r] - VinR[j][mt][r], 0.f);
    __syncthreads();

    // ---- phase iii: dV = V @ G + R @ Pt; momentum into Dreg (V unchanged) ----
#pragma unroll
    for (int h = 0; h < 2; ++h) {   // n-tiles in halves of 4 (keeps live regs low)
      f4_t dacc[4][2];
#pragma unroll
      for (int nn = 0; nn < 4; ++nn) { dacc[nn][0] = (f4_t)0.f; dacc[nn][1] = (f4_t)0.f; }

#pragma unroll
      for (int k = 0; k < 16; ++k) {   // K = 512 (V @ G)
        bh8_t a[2];
#pragma unroll
        for (int mt = 0; mt < 2; ++mt) {
          const float* vp = Vf32 + (16u * mt + lr) * VSTRIDE + k * 32 + lq * 8u;
          a[mt] = cvt8(*(const f4_t*)vp, *(const f4_t*)(vp + 4));
        }
#pragma unroll
        for (int nn = 0; nn < 4; ++nn) {
          unsigned n = 8u * w + 4u * h + nn;
          bh8_t b = *(const bh8_t*)(G + (16u * n + lr) * 512u + k * 32 + lq * 8u);
#pragma unroll
          for (int mt = 0; mt < 2; ++mt) dacc[nn][mt] = MFMA16(a[mt], b, dacc[nn][mt]);
        }
      }
#pragma unroll
      for (int k = 0; k < 4; ++k) {    // K = 128 (R @ Pt)
        bh8_t a[2];
#pragma unroll
        for (int mt = 0; mt < 2; ++mt)
          a[mt] = *(const bh8_t*)(R_lds + (16u * mt + lr) * 136u + k * 32 + lq * 8u);
#pragma unroll
        for (int nn = 0; nn < 4; ++nn) {
          unsigned n = 8u * w + 4u * h + nn;
          bh8_t b = *(const bh8_t*)(Pt + (16u * n + lr) * 128u + k * 32 + lq * 8u);
#pragma unroll
          for (int mt = 0; mt < 2; ++mt) dacc[nn][mt] = MFMA16(a[mt], b, dacc[nn][mt]);
        }
      }
      // momentum update (reads OLD V; no V writes until after sync)
#pragma unroll
      for (int nn = 0; nn < 4; ++nn)
#pragma unroll
        for (int mt = 0; mt < 2; ++mt)
#pragma unroll
          for (int r = 0; r < 4; ++r) {
            unsigned idx = (16u * mt + 4u * lq + r) * VSTRIDE + 16u * (8u * w + 4u * h + nn) + lr;
            float v = Vf32[idx];
            float dv = dacc[nn][mt][r] + fminf(v, 0.f) * 0.00390625f;
            float d = 0.9f * Dreg[mt][4 * h + nn][r] - 0.01f * dv;
            Dreg[mt][4 * h + nn][r] = d;
          }
    }
    __syncthreads();  // all A-reads of old V complete

    // ---- apply V += diff (wave-disjoint columns) ----
#pragma unroll
    for (int nn = 0; nn < 8; ++nn)
#pragma unroll
      for (int mt = 0; mt < 2; ++mt)
#pragma unroll
        for (int r = 0; r < 4; ++r) {
          unsigned idx = (16u * mt + 4u * lq + r) * VSTRIDE + 16u * (8u * w + nn) + lr;
          Vf32[idx] += Dreg[mt][nn][r];
        }
    __syncthreads();  // new V visible before next phase-ii reads
  }

  // ---- write final V (fp32) from LDS to out ----
#pragma unroll
  for (int p = 0; p < 16; ++p) {
    unsigned i4 = (p * 256u + tid) * 4u;       // 16384 f32 per block
    unsigned r = i4 >> 9, c = i4 & 511u;
    *(f4_t*)(out + (row0 + r) * 512u + c) = *(const f4_t*)(Vf32 + r * VSTRIDE + c);
  }
}

extern "C" void kernel_launch(void* const* d_in, const int* in_sizes, int n_in,
                              void* d_out, int out_size, void* d_ws, size_t ws_size,
                              hipStream_t stream) {
  const float* input = (const float*)d_in[0];
  // d_in[1] = Vref (unused by reference)
  const float* Vin = (const float*)d_in[2];
  const float* W1  = (const float*)d_in[3];
  const float* b1  = (const float*)d_in[4];
  const float* W2  = (const float*)d_in[5];
  const float* b2  = (const float*)d_in[6];
  const float* S   = (const float*)d_in[7];
  const float* Pin = (const float*)d_in[8];
  const int* nit   = (const int*)d_in[9];
  bhalf* ws  = (bhalf*)d_ws;
  float* out = (float*)d_out;

  amn_prep<<<3072, 256, 0, stream>>>(W1, W2, Pin, ws);
  amn_gram<<<1024, 256, 0, stream>>>(S, ws);
  amn_main<<<1024, 256, 0, stream>>>(input, Vin, b1, b2, nit, ws, out);
}

// Round 8
// 2508.121 us; speedup vs baseline: 2.7125x; 1.4130x over previous
//
#include <hip/hip_runtime.h>

typedef __bf16 bhalf;
typedef __bf16 bh8_t __attribute__((ext_vector_type(8)));
typedef float f4_t __attribute__((ext_vector_type(4)));

#define MFMA16(A, B, C) __builtin_amdgcn_mfma_f32_16x16x32_bf16((A), (B), (C), 0, 0, 0)

// Problem: B=32768, D_IN=128, H=1024, N_FLUX=512, N_MET=256, N_IN=128
//
// ROUND 8: break the spill->L2-thrash->latency cycle via high occupancy by
// construction. M=32 rows/block, 512 threads (8 waves, 128-VGPR budget),
// 1024 blocks. Per-thread state: Vreg f32 32 + diff PACKED bf16 16 + Vin
// packed 4 = 52 regs; transients bounded (acc<=16, shallow unrolls, all MFMA
// A/B operands loaded directly as bf16x8 -> no f32 transients in hot loops).
// G-fold (G = S^T S * 2/256, symmetric) removes the T intermediate: LDS = 66KB
// -> 2 blocks/CU = 16 waves/CU = 4 waves/SIMD (4 x 128 = 512-reg pool exactly).

#define OFF_W1T  0
#define OFF_W2T  (OFF_W1T + 1024 * 128)
#define OFF_PINB (OFF_W2T + 512 * 1024)
#define OFF_PT   (OFF_PINB + 128 * 512)
#define OFF_G    (OFF_PT + 512 * 128)

__global__ __launch_bounds__(256) void amn_prep(
    const float* __restrict__ W1, const float* __restrict__ W2,
    const float* __restrict__ Pin, bhalf* __restrict__ ws) {
  unsigned i = blockIdx.x * 256u + threadIdx.x;
  if (i < 131072u) {                   // W1t[n][k] = W1[k][n]
    unsigned n = i >> 7, k = i & 127u;
    ws[OFF_W1T + i] = (bhalf)W1[k * 1024u + n];
  } else if (i < 655360u) {            // W2t[n][k] = W2[k][n]
    unsigned j = i - 131072u;
    unsigned n = j >> 10, k = j & 1023u;
    ws[OFF_W2T + j] = (bhalf)W2[k * 512u + n];
  } else if (i < 720896u) {            // Pinb = bf16(Pin)
    unsigned j = i - 655360u;
    ws[OFF_PINB + j] = (bhalf)Pin[j];
  } else if (i < 786432u) {            // Pt[n][k] = Pin[k][n] * 2/128
    unsigned j = i - 720896u;
    unsigned n = j >> 7, k = j & 127u;
    ws[OFF_PT + j] = (bhalf)(Pin[k * 512u + n] * 0.015625f);
  }
}

// G[i][j] = (2/256) * sum_k S[k][i]*S[k][j]
__global__ __launch_bounds__(256) void amn_gram(
    const float* __restrict__ S, bhalf* __restrict__ ws) {
  const unsigned bi = blockIdx.x >> 5, bj = blockIdx.x & 31u;
  __shared__ float SA[256][16];
  __shared__ float SB[256][16];
  const unsigned t = threadIdx.x;
#pragma unroll
  for (int p = 0; p < 16; ++p) {
    unsigned e = p * 256u + t;
    unsigned k = e >> 4, c = e & 15u;
    SA[k][c] = S[k * 512u + bi * 16u + c];
    SB[k][c] = S[k * 512u + bj * 16u + c];
  }
  __syncthreads();
  const unsigned ti = t >> 4, tj = t & 15u;
  float acc = 0.f;
#pragma unroll 8
  for (int k = 0; k < 256; ++k) acc += SA[k][ti] * SB[k][tj];
  ws[OFF_G + (bi * 16u + ti) * 512u + bj * 16u + tj] = (bhalf)(acc * 0.0078125f);
}

__device__ inline bh8_t cvt8(f4_t f0, f4_t f1) {
  bh8_t r;
  r[0] = (bhalf)f0[0]; r[1] = (bhalf)f0[1]; r[2] = (bhalf)f0[2]; r[3] = (bhalf)f0[3];
  r[4] = (bhalf)f1[0]; r[5] = (bhalf)f1[1]; r[6] = (bhalf)f1[2]; r[7] = (bhalf)f1[3];
  return r;
}

__device__ inline unsigned pk2(float a, float b) {
  union { bhalf h; unsigned short s; } x, y;
  x.h = (bhalf)a; y.h = (bhalf)b;
  return (unsigned)x.s | ((unsigned)y.s << 16);
}
__device__ inline float up_lo(unsigned u) {
  union { unsigned u; float f; } t; t.u = u << 16; return t.f;
}
__device__ inline float up_hi(unsigned u) {
  union { unsigned u; float f; } t; t.u = u & 0xffff0000u; return t.f;
}

// LDS (bytes, total 66,048 -> 2 blocks/CU):
//   V_lds [32][520] bf16 @ 0      (33,280)  loop phase
//   R_lds [32][136] bf16 @ 33280  ( 8,704)  loop phase
//   hid   [32][1032] bf16 @ 0     (66,048)  MLP phase only (aliases both)
#define SMEM_BYTES 66048

__global__ __launch_bounds__(512) void amn_main(
    const float* __restrict__ input, const float* __restrict__ Vin,
    const float* __restrict__ b1, const float* __restrict__ b2,
    const int* __restrict__ niter_p,
    const bhalf* __restrict__ ws, float* __restrict__ out) {

  const unsigned tid = threadIdx.x;
  const unsigned w  = tid >> 6;    // wave 0..7
  const unsigned l  = tid & 63u;
  const unsigned lq = l >> 4;      // 0..3
  const unsigned lr = l & 15u;     // 0..15
  const unsigned row0 = blockIdx.x * 32u;

  const bhalf* W1t  = ws + OFF_W1T;
  const bhalf* W2t  = ws + OFF_W2T;
  const bhalf* Pinb = ws + OFF_PINB;
  const bhalf* Pt   = ws + OFF_PT;
  const bhalf* G    = ws + OFF_G;

  __shared__ __align__(16) unsigned char smem[SMEM_BYTES];
  bhalf* hid_lds = (bhalf*)smem;                 // [32][1032]
  bhalf* V_lds   = (bhalf*)smem;                 // [32][520]
  bhalf* R_lds   = (bhalf*)(smem + 33280);       // [32][136]

  // ===== MLP1: hidden = relu(input @ W1 + b1); wave w owns tiles 8w..8w+7 =====
  {
    f4_t hacc[2][8];
#pragma unroll
    for (int mt = 0; mt < 2; ++mt)
#pragma unroll
      for (int t = 0; t < 8; ++t) hacc[mt][t] = (f4_t)0.f;

#pragma unroll
    for (int k = 0; k < 4; ++k) {   // K = 128
      bh8_t a[2];
#pragma unroll
      for (int mt = 0; mt < 2; ++mt) {
        const float* ap = input + (row0 + 16u * mt + lr) * 128u + k * 32 + lq * 8u;
        a[mt] = cvt8(*(const f4_t*)ap, *(const f4_t*)(ap + 4));
      }
#pragma unroll
      for (int t = 0; t < 8; ++t) {
        bh8_t b = *(const bh8_t*)(W1t + (16u * (8u * w + t) + lr) * 128u + k * 32 + lq * 8u);
#pragma unroll
        for (int mt = 0; mt < 2; ++mt) hacc[mt][t] = MFMA16(a[mt], b, hacc[mt][t]);
      }
    }
#pragma unroll
    for (int t = 0; t < 8; ++t) {
      unsigned col = 16u * (8u * w + t) + lr;
      float bias = b1[col];
#pragma unroll
      for (int mt = 0; mt < 2; ++mt)
#pragma unroll
        for (int r = 0; r < 4; ++r)
          hid_lds[(16u * mt + 4u * lq + r) * 1032u + col] =
              (bhalf)fmaxf(hacc[mt][t][r] + bias, 0.f);
    }
  }
  __syncthreads();

  // ===== MLP2: V0 = hidden @ W2 + b2; wave w owns V n-tiles 4w..4w+3 =====
  f4_t Vreg[2][4];
#pragma unroll
  for (int mt = 0; mt < 2; ++mt)
#pragma unroll
    for (int n = 0; n < 4; ++n) Vreg[mt][n] = (f4_t)0.f;

#pragma unroll 2
  for (int k = 0; k < 32; ++k) {  // K = 1024
    bh8_t a[2];
#pragma unroll
    for (int mt = 0; mt < 2; ++mt)
      a[mt] = *(const bh8_t*)(hid_lds + (16u * mt + lr) * 1032u + k * 32 + lq * 8u);
#pragma unroll
    for (int n = 0; n < 4; ++n) {
      bh8_t b = *(const bh8_t*)(W2t + (16u * (4u * w + n) + lr) * 1024u + k * 32 + lq * 8u);
#pragma unroll
      for (int mt = 0; mt < 2; ++mt) Vreg[mt][n] = MFMA16(a[mt], b, Vreg[mt][n]);
    }
  }
#pragma unroll
  for (int n = 0; n < 4; ++n) {
    float bias = b2[16u * (4u * w + n) + lr];
#pragma unroll
    for (int mt = 0; mt < 2; ++mt)
#pragma unroll
      for (int r = 0; r < 4; ++r) Vreg[mt][n][r] += bias;
  }

  // ---- Vin for u-tile w (1 per wave), packed bf16: 4 regs ----
  unsigned Vinpk[2][2];
#pragma unroll
  for (int mt = 0; mt < 2; ++mt) {
    float vi[4];
#pragma unroll
    for (int r = 0; r < 4; ++r)
      vi[r] = Vin[(row0 + 16u * mt + 4u * lq + r) * 128u + 16u * w + lr];
    Vinpk[mt][0] = pk2(vi[0], vi[1]);
    Vinpk[mt][1] = pk2(vi[2], vi[3]);
  }

  // ---- diff state, packed bf16: 16 regs ----
  unsigned Dpk[2][4][2];
#pragma unroll
  for (int mt = 0; mt < 2; ++mt)
#pragma unroll
    for (int n = 0; n < 4; ++n) { Dpk[mt][n][0] = 0u; Dpk[mt][n][1] = 0u; }

  __syncthreads();  // hid reads done; V_lds/R_lds region reusable

  // ================= 30 momentum iterations =================
  const int niter = niter_p[0];
  for (int it = 0; it < niter; ++it) {
    // ---- (i) stage V (bf16) ----
#pragma unroll
    for (int mt = 0; mt < 2; ++mt)
#pragma unroll
      for (int n = 0; n < 4; ++n) {
        unsigned col = 16u * (4u * w + n) + lr;
#pragma unroll
        for (int r = 0; r < 4; ++r)
          V_lds[(16u * mt + 4u * lq + r) * 520u + col] = (bhalf)Vreg[mt][n][r];
      }
    __syncthreads();

    // ---- (ii) U = V @ Pin^T for u-tile w; R = relu(U - Vin) ----
    {
      f4_t acc[2];
      acc[0] = (f4_t)0.f; acc[1] = (f4_t)0.f;
#pragma unroll 4
      for (int k = 0; k < 16; ++k) {   // K = 512
        bh8_t a0 = *(const bh8_t*)(V_lds + lr * 520u + k * 32 + lq * 8u);
        bh8_t a1 = *(const bh8_t*)(V_lds + (16u + lr) * 520u + k * 32 + lq * 8u);
        bh8_t b = *(const bh8_t*)(Pinb + (16u * w + lr) * 512u + k * 32 + lq * 8u);
        acc[0] = MFMA16(a0, b, acc[0]);
        acc[1] = MFMA16(a1, b, acc[1]);
      }
#pragma unroll
      for (int mt = 0; mt < 2; ++mt) {
        float v0 = up_lo(Vinpk[mt][0]), v1 = up_hi(Vinpk[mt][0]);
        float v2 = up_lo(Vinpk[mt][1]), v3 = up_hi(Vinpk[mt][1]);
        unsigned base = (16u * mt + 4u * lq) * 136u + 16u * w + lr;
        R_lds[base]            = (bhalf)fmaxf(acc[mt][0] - v0, 0.f);
        R_lds[base + 136u]     = (bhalf)fmaxf(acc[mt][1] - v1, 0.f);
        R_lds[base + 272u]     = (bhalf)fmaxf(acc[mt][2] - v2, 0.f);
        R_lds[base + 408u]     = (bhalf)fmaxf(acc[mt][3] - v3, 0.f);
      }
    }
    __syncthreads();

    // ---- (iii) dV = V @ G + R @ Pt for n-tiles {4w..4w+3}, halves of 2 ----
#pragma unroll
    for (int h = 0; h < 2; ++h) {
      f4_t dacc[2][2];   // [nn][mt]
#pragma unroll
      for (int nn = 0; nn < 2; ++nn) { dacc[nn][0] = (f4_t)0.f; dacc[nn][1] = (f4_t)0.f; }

#pragma unroll 2
      for (int k = 0; k < 16; ++k) {   // K = 512 (V @ G)
        bh8_t a0 = *(const bh8_t*)(V_lds + lr * 520u + k * 32 + lq * 8u);
        bh8_t a1 = *(const bh8_t*)(V_lds + (16u + lr) * 520u + k * 32 + lq * 8u);
#pragma unroll
        for (int nn = 0; nn < 2; ++nn) {
          unsigned n = 4u * w + 2u * h + nn;
          bh8_t b = *(const bh8_t*)(G + (16u * n + lr) * 512u + k * 32 + lq * 8u);
          dacc[nn][0] = MFMA16(a0, b, dacc[nn][0]);
          dacc[nn][1] = MFMA16(a1, b, dacc[nn][1]);
        }
      }
#pragma unroll
      for (int k = 0; k < 4; ++k) {    // K = 128 (R @ Pt)
        bh8_t a0 = *(const bh8_t*)(R_lds + lr * 136u + k * 32 + lq * 8u);
        bh8_t a1 = *(const bh8_t*)(R_lds + (16u + lr) * 136u + k * 32 + lq * 8u);
#pragma unroll
        for (int nn = 0; nn < 2; ++nn) {
          unsigned n = 4u * w + 2u * h + nn;
          bh8_t b = *(const bh8_t*)(Pt + (16u * n + lr) * 128u + k * 32 + lq * 8u);
          dacc[nn][0] = MFMA16(a0, b, dacc[nn][0]);
          dacc[nn][1] = MFMA16(a1, b, dacc[nn][1]);
        }
      }

      // momentum update for local n-tiles 2h+nn (full-precision d into V,
      // rounded d carried as packed bf16 momentum)
#pragma unroll
      for (int nn = 0; nn < 2; ++nn) {
        int nl = 2 * h + nn;
#pragma unroll
        for (int mt = 0; mt < 2; ++mt) {
          float dv0 = dacc[nn][mt][0] + fminf(Vreg[mt][nl][0], 0.f) * 0.00390625f;
          float dv1 = dacc[nn][mt][1] + fminf(Vreg[mt][nl][1], 0.f) * 0.00390625f;
          float dv2 = dacc[nn][mt][2] + fminf(Vreg[mt][nl][2], 0.f) * 0.00390625f;
          float dv3 = dacc[nn][mt][3] + fminf(Vreg[mt][nl][3], 0.f) * 0.00390625f;
          float d0 = 0.9f * up_lo(Dpk[mt][nl][0]) - 0.01f * dv0;
          float d1 = 0.9f * up_hi(Dpk[mt][nl][0]) - 0.01f * dv1;
          float d2 = 0.9f * up_lo(Dpk[mt][nl][1]) - 0.01f * dv2;
          float d3 = 0.9f * up_hi(Dpk[mt][nl][1]) - 0.01f * dv3;
          Vreg[mt][nl][0] += d0; Vreg[mt][nl][1] += d1;
          Vreg[mt][nl][2] += d2; Vreg[mt][nl][3] += d3;
          Dpk[mt][nl][0] = pk2(d0, d1);
          Dpk[mt][nl][1] = pk2(d2, d3);
        }
      }
    }
    __syncthreads();   // V_lds reads complete before next iter's restage
  }

  // ---- write final V ----
#pragma unroll
  for (int mt = 0; mt < 2; ++mt)
#pragma unroll
    for (int n = 0; n < 4; ++n) {
      unsigned col = 16u * (4u * w + n) + lr;
#pragma unroll
      for (int r = 0; r < 4; ++r)
        out[(row0 + 16u * mt + 4u * lq + r) * 512u + col] = Vreg[mt][n][r];
    }
}

extern "C" void kernel_launch(void* const* d_in, const int* in_sizes, int n_in,
                              void* d_out, int out_size, void* d_ws, size_t ws_size,
                              hipStream_t stream) {
  const float* input = (const float*)d_in[0];
  // d_in[1] = Vref (unused by reference)
  const float* Vin = (const float*)d_in[2];
  const float* W1  = (const float*)d_in[3];
  const float* b1  = (const float*)d_in[4];
  const float* W2  = (const float*)d_in[5];
  const float* b2  = (const float*)d_in[6];
  const float* S   = (const float*)d_in[7];
  const float* Pin = (const float*)d_in[8];
  const int* nit   = (const int*)d_in[9];
  bhalf* ws  = (bhalf*)d_ws;
  float* out = (float*)d_out;

  amn_prep<<<3072, 256, 0, stream>>>(W1, W2, Pin, ws);
  amn_gram<<<1024, 256, 0, stream>>>(S, ws);
  amn_main<<<1024, 512, 0, stream>>>(input, Vin, b1, b2, nit, ws, out);
}

// Round 9
// 1721.336 us; speedup vs baseline: 3.9523x; 1.4571x over previous
//
#include <hip/hip_runtime.h>

typedef __bf16 bhalf;
typedef __bf16 bh8_t __attribute__((ext_vector_type(8)));
typedef float f4_t __attribute__((ext_vector_type(4)));

#define MFMA16(A, B, C) __builtin_amdgcn_mfma_f32_16x16x32_bf16((A), (B), (C), 0, 0, 0)

// Problem: B=32768, D_IN=128, H=1024, N_FLUX=512, N_MET=256, N_IN=128
//
// ROUND 9: r8 eliminated spill/HBM; remaining wall = scattered B-panel reads
// (G/Pinb/Pt, 768 KB/iter/block) thrash L1 -> L1-miss-path caps per-CU L2 BW
// at ~26%. Fix: stream B-panels via global_load_lds (bypasses L1/VGPR),
// double-buffered k=32 chunks, counted vmcnt(5)/(4) so next chunk's DMA stays
// in flight across raw s_barriers (T3/T4). Phase ii fused into the G k-loop.
// M=32, 512 thr (8 waves, 128-VGPR budget), 1024 blocks - r8's no-spill shape.

#define OFF_W1T  0
#define OFF_W2T  (OFF_W1T + 1024 * 128)
#define OFF_PINB (OFF_W2T + 512 * 1024)
#define OFF_PT   (OFF_PINB + 128 * 512)
#define OFF_G    (OFF_PT + 512 * 128)

__global__ __launch_bounds__(256) void amn_prep(
    const float* __restrict__ W1, const float* __restrict__ W2,
    const float* __restrict__ Pin, bhalf* __restrict__ ws) {
  unsigned i = blockIdx.x * 256u + threadIdx.x;
  if (i < 131072u) {                   // W1t[n][k] = W1[k][n]
    unsigned n = i >> 7, k = i & 127u;
    ws[OFF_W1T + i] = (bhalf)W1[k * 1024u + n];
  } else if (i < 655360u) {            // W2t[n][k] = W2[k][n]
    unsigned j = i - 131072u;
    unsigned n = j >> 10, k = j & 1023u;
    ws[OFF_W2T + j] = (bhalf)W2[k * 512u + n];
  } else if (i < 720896u) {            // Pinb = bf16(Pin)
    unsigned j = i - 655360u;
    ws[OFF_PINB + j] = (bhalf)Pin[j];
  } else if (i < 786432u) {            // Pt[n][k] = Pin[k][n] * 2/128
    unsigned j = i - 720896u;
    unsigned n = j >> 7, k = j & 127u;
    ws[OFF_PT + j] = (bhalf)(Pin[k * 512u + n] * 0.015625f);
  }
}

// G[i][j] = (2/256) * sum_k S[k][i]*S[k][j]
__global__ __launch_bounds__(256) void amn_gram(
    const float* __restrict__ S, bhalf* __restrict__ ws) {
  const unsigned bi = blockIdx.x >> 5, bj = blockIdx.x & 31u;
  __shared__ float SA[256][16];
  __shared__ float SB[256][16];
  const unsigned t = threadIdx.x;
#pragma unroll
  for (int p = 0; p < 16; ++p) {
    unsigned e = p * 256u + t;
    unsigned k = e >> 4, c = e & 15u;
    SA[k][c] = S[k * 512u + bi * 16u + c];
    SB[k][c] = S[k * 512u + bj * 16u + c];
  }
  __syncthreads();
  const unsigned ti = t >> 4, tj = t & 15u;
  float acc = 0.f;
#pragma unroll 8
  for (int k = 0; k < 256; ++k) acc += SA[k][ti] * SB[k][tj];
  ws[OFF_G + (bi * 16u + ti) * 512u + bj * 16u + tj] = (bhalf)(acc * 0.0078125f);
}

__device__ inline bh8_t cvt8(f4_t f0, f4_t f1) {
  bh8_t r;
  r[0] = (bhalf)f0[0]; r[1] = (bhalf)f0[1]; r[2] = (bhalf)f0[2]; r[3] = (bhalf)f0[3];
  r[4] = (bhalf)f1[0]; r[5] = (bhalf)f1[1]; r[6] = (bhalf)f1[2]; r[7] = (bhalf)f1[3];
  return r;
}
__device__ inline unsigned pk2(float a, float b) {
  union { bhalf h; unsigned short s; } x, y;
  x.h = (bhalf)a; y.h = (bhalf)b;
  return (unsigned)x.s | ((unsigned)y.s << 16);
}
__device__ inline float up_lo(unsigned u) {
  union { unsigned u; float f; } t; t.u = u << 16; return t.f;
}
__device__ inline float up_hi(unsigned u) {
  union { unsigned u; float f; } t; t.u = u & 0xffff0000u; return t.f;
}

__device__ inline void gload16(const void* g, void* l) {
  __builtin_amdgcn_global_load_lds(
      (const __attribute__((address_space(1))) void*)g,
      (__attribute__((address_space(3))) void*)l, 16, 0, 0);
}

// LDS (bytes, total 123,904):
//   V_lds [32][520] bf16 @ 0       (33,280)
//   R_lds [32][136] bf16 @ 33280   ( 8,704)
//   buf0: G-chunk 32,768 + P-chunk 8,192 @ 41,984
//   buf1: G-chunk 32,768 + P-chunk 8,192 @ 82,944
//   hid [32][1032] bf16 @ 0 (66,048; MLP phase only, aliases V/R/buf0-head)
#define SMV   0
#define SMR   33280
#define SMB0  41984
#define BUFSTEP 40960
#define GSZ   32768
#define SMEM_BYTES 123904

__global__ __launch_bounds__(512) void amn_main(
    const float* __restrict__ input, const float* __restrict__ Vin,
    const float* __restrict__ b1, const float* __restrict__ b2,
    const int* __restrict__ niter_p,
    const bhalf* __restrict__ ws, float* __restrict__ out) {

  const unsigned tid = threadIdx.x;
  const unsigned w  = tid >> 6;    // wave 0..7
  const unsigned l  = tid & 63u;
  const unsigned lq = l >> 4;      // 0..3
  const unsigned lr = l & 15u;     // 0..15
  const unsigned row0 = blockIdx.x * 32u;
  const unsigned rq = l >> 2;          // staging: row-in-seg 0..15
  const unsigned c16 = (l & 3u) * 16u; // staging: byte-in-row 0..48

  const bhalf* W1t  = ws + OFF_W1T;
  const bhalf* W2t  = ws + OFF_W2T;

  __shared__ __align__(16) unsigned char smem[SMEM_BYTES];
  bhalf* hid_lds = (bhalf*)smem;             // [32][1032]
  bhalf* V_lds   = (bhalf*)(smem + SMV);     // [32][520]
  bhalf* R_lds   = (bhalf*)(smem + SMR);     // [32][136]

  // ===== MLP1: hidden = relu(input @ W1 + b1); wave w owns tiles 8w..8w+7 =====
  {
    f4_t hacc[2][8];
#pragma unroll
    for (int mt = 0; mt < 2; ++mt)
#pragma unroll
      for (int t = 0; t < 8; ++t) hacc[mt][t] = (f4_t)0.f;

#pragma unroll
    for (int k = 0; k < 4; ++k) {   // K = 128
      bh8_t a[2];
#pragma unroll
      for (int mt = 0; mt < 2; ++mt) {
        const float* ap = input + (row0 + 16u * mt + lr) * 128u + k * 32 + lq * 8u;
        a[mt] = cvt8(*(const f4_t*)ap, *(const f4_t*)(ap + 4));
      }
#pragma unroll
      for (int t = 0; t < 8; ++t) {
        bh8_t b = *(const bh8_t*)(W1t + (16u * (8u * w + t) + lr) * 128u + k * 32 + lq * 8u);
#pragma unroll
        for (int mt = 0; mt < 2; ++mt) hacc[mt][t] = MFMA16(a[mt], b, hacc[mt][t]);
      }
    }
#pragma unroll
    for (int t = 0; t < 8; ++t) {
      unsigned col = 16u * (8u * w + t) + lr;
      float bias = b1[col];
#pragma unroll
      for (int mt = 0; mt < 2; ++mt)
#pragma unroll
        for (int r = 0; r < 4; ++r)
          hid_lds[(16u * mt + 4u * lq + r) * 1032u + col] =
              (bhalf)fmaxf(hacc[mt][t][r] + bias, 0.f);
    }
  }
  __syncthreads();

  // ===== MLP2: V0 = hidden @ W2 + b2; wave w owns V n-tiles 4w..4w+3 =====
  f4_t Vreg[2][4];
#pragma unroll
  for (int mt = 0; mt < 2; ++mt)
#pragma unroll
    for (int n = 0; n < 4; ++n) Vreg[mt][n] = (f4_t)0.f;

#pragma unroll 2
  for (int k = 0; k < 32; ++k) {  // K = 1024
    bh8_t a[2];
#pragma unroll
    for (int mt = 0; mt < 2; ++mt)
      a[mt] = *(const bh8_t*)(hid_lds + (16u * mt + lr) * 1032u + k * 32 + lq * 8u);
#pragma unroll
    for (int n = 0; n < 4; ++n) {
      bh8_t b = *(const bh8_t*)(W2t + (16u * (4u * w + n) + lr) * 1024u + k * 32 + lq * 8u);
#pragma unroll
      for (int mt = 0; mt < 2; ++mt) Vreg[mt][n] = MFMA16(a[mt], b, Vreg[mt][n]);
    }
  }
#pragma unroll
  for (int n = 0; n < 4; ++n) {
    float bias = b2[16u * (4u * w + n) + lr];
#pragma unroll
    for (int mt = 0; mt < 2; ++mt)
#pragma unroll
      for (int r = 0; r < 4; ++r) Vreg[mt][n][r] += bias;
  }

  // ---- Vin for u-tile w, packed bf16: 4 regs ----
  unsigned Vinpk[2][2];
#pragma unroll
  for (int mt = 0; mt < 2; ++mt) {
    float vi[4];
#pragma unroll
    for (int r = 0; r < 4; ++r)
      vi[r] = Vin[(row0 + 16u * mt + 4u * lq + r) * 128u + 16u * w + lr];
    Vinpk[mt][0] = pk2(vi[0], vi[1]);
    Vinpk[mt][1] = pk2(vi[2], vi[3]);
  }

  // ---- diff state, packed bf16: 16 regs ----
  unsigned Dpk[2][4][2];
#pragma unroll
  for (int mt = 0; mt < 2; ++mt)
#pragma unroll
    for (int n = 0; n < 4; ++n) { Dpk[mt][n][0] = 0u; Dpk[mt][n][1] = 0u; }

  const int niter = niter_p[0];

  // force all prior vmem consumed so vmcnt counting below is exact
  asm volatile("s_waitcnt vmcnt(0)" ::: "memory");
  __syncthreads();  // hid reads done; V/R/buf regions reusable

  const char* Gb  = (const char*)(ws + OFF_G);
  const char* Pb  = (const char*)(ws + OFF_PINB);
  const char* Ptb = (const char*)(ws + OFF_PT);

  // ================= 30 momentum iterations =================
  for (int it = 0; it < niter; ++it) {
    // ---- (i) stage V (bf16) ----
#pragma unroll
    for (int mt = 0; mt < 2; ++mt)
#pragma unroll
      for (int n = 0; n < 4; ++n) {
        unsigned col = 16u * (4u * w + n) + lr;
#pragma unroll
        for (int r = 0; r < 4; ++r)
          V_lds[(16u * mt + 4u * lq + r) * 520u + col] = (bhalf)Vreg[mt][n][r];
      }
    __syncthreads();  // safe: vmcnt==0 at iter start

    f4_t dacc[4][2];
#pragma unroll
    for (int nt = 0; nt < 4; ++nt) { dacc[nt][0] = (f4_t)0.f; dacc[nt][1] = (f4_t)0.f; }
    f4_t Uacc[2];
    Uacc[0] = (f4_t)0.f; Uacc[1] = (f4_t)0.f;

    // prologue: stage chunk 0 (G k=0..31 + Pinb k=0..31) into buf0
    {
      unsigned b = SMB0;
#pragma unroll
      for (int i = 0; i < 4; ++i) {
        unsigned s = w + 8u * i;
        gload16(Gb + ((16u * s + rq) * 512u) * 2u + c16, smem + b + s * 1024u);
      }
      gload16(Pb + ((16u * w + rq) * 512u) * 2u + c16, smem + b + GSZ + w * 1024u);
    }

    // ---- fused phase (ii)+(iii-G): for each k-chunk t: dacc += V@G, Uacc += V@Pin^T
#pragma unroll 1
    for (int t = 0; t < 16; ++t) {
      asm volatile("s_waitcnt lgkmcnt(0)" ::: "memory");
      __builtin_amdgcn_s_barrier();            // buf[(t+1)&1] free to overwrite
      __builtin_amdgcn_sched_barrier(0);
      if (t < 15) {
        unsigned u = (unsigned)t + 1u;
        unsigned b = SMB0 + (u & 1u) * BUFSTEP;
#pragma unroll
        for (int i = 0; i < 4; ++i) {
          unsigned s = w + 8u * i;
          gload16(Gb + ((16u * s + rq) * 512u + u * 32u) * 2u + c16, smem + b + s * 1024u);
        }
        gload16(Pb + ((16u * w + rq) * 512u + u * 32u) * 2u + c16, smem + b + GSZ + w * 1024u);
        asm volatile("s_waitcnt vmcnt(5)" ::: "memory");   // chunk t landed
      } else {
        // stage Pt chunk 0 into buf0 ((16)&1 == 0)
        unsigned b = SMB0;
#pragma unroll
        for (int i = 0; i < 4; ++i) {
          unsigned s = w + 8u * i;
          gload16(Ptb + ((16u * s + rq) * 128u) * 2u + c16, smem + b + s * 1024u);
        }
        asm volatile("s_waitcnt vmcnt(4)" ::: "memory");   // chunk 15 landed
      }
      __builtin_amdgcn_s_barrier();            // chunk t valid for all waves
      __builtin_amdgcn_sched_barrier(0);

      const bhalf* gb = (const bhalf*)(smem + SMB0 + ((unsigned)t & 1u) * BUFSTEP);
      const bhalf* pb = gb + GSZ / 2;
      bh8_t a0 = *(const bh8_t*)(V_lds + lr * 520u + t * 32 + lq * 8u);
      bh8_t a1 = *(const bh8_t*)(V_lds + (16u + lr) * 520u + t * 32 + lq * 8u);
#pragma unroll
      for (int nt = 0; nt < 4; ++nt) {
        bh8_t bfr = *(const bh8_t*)(gb + (16u * (4u * w + nt) + lr) * 32u + lq * 8u);
        dacc[nt][0] = MFMA16(a0, bfr, dacc[nt][0]);
        dacc[nt][1] = MFMA16(a1, bfr, dacc[nt][1]);
      }
      bh8_t pf = *(const bh8_t*)(pb + (16u * w + lr) * 32u + lq * 8u);
      Uacc[0] = MFMA16(a0, pf, Uacc[0]);
      Uacc[1] = MFMA16(a1, pf, Uacc[1]);
    }

    // ---- R = relu(U - Vin) -> LDS ----
#pragma unroll
    for (int mt = 0; mt < 2; ++mt) {
      float v0 = up_lo(Vinpk[mt][0]), v1 = up_hi(Vinpk[mt][0]);
      float v2 = up_lo(Vinpk[mt][1]), v3 = up_hi(Vinpk[mt][1]);
      unsigned base = (16u * mt + 4u * lq) * 136u + 16u * w + lr;
      R_lds[base]        = (bhalf)fmaxf(Uacc[mt][0] - v0, 0.f);
      R_lds[base + 136u] = (bhalf)fmaxf(Uacc[mt][1] - v1, 0.f);
      R_lds[base + 272u] = (bhalf)fmaxf(Uacc[mt][2] - v2, 0.f);
      R_lds[base + 408u] = (bhalf)fmaxf(Uacc[mt][3] - v3, 0.f);
    }

    // ---- phase (iii-Pt): dacc += R @ Pt, staged chunks kc2 = 0..3 ----
#pragma unroll 1
    for (int t2 = 0; t2 < 4; ++t2) {
      asm volatile("s_waitcnt lgkmcnt(0)" ::: "memory");
      __builtin_amdgcn_s_barrier();            // R visible; buf[(t2+1)&1] free
      __builtin_amdgcn_sched_barrier(0);
      if (t2 < 3) {
        unsigned kc2 = (unsigned)t2 + 1u;
        unsigned b = SMB0 + (kc2 & 1u) * BUFSTEP;
#pragma unroll
        for (int i = 0; i < 4; ++i) {
          unsigned s = w + 8u * i;
          gload16(Ptb + ((16u * s + rq) * 128u + kc2 * 32u) * 2u + c16, smem + b + s * 1024u);
        }
        asm volatile("s_waitcnt vmcnt(4)" ::: "memory");
      } else {
        asm volatile("s_waitcnt vmcnt(0)" ::: "memory");
      }
      __builtin_amdgcn_s_barrier();
      __builtin_amdgcn_sched_barrier(0);

      const bhalf* gb = (const bhalf*)(smem + SMB0 + ((unsigned)t2 & 1u) * BUFSTEP);
      bh8_t a0 = *(const bh8_t*)(R_lds + lr * 136u + t2 * 32 + lq * 8u);
      bh8_t a1 = *(const bh8_t*)(R_lds + (16u + lr) * 136u + t2 * 32 + lq * 8u);
#pragma unroll
      for (int nt = 0; nt < 4; ++nt) {
        bh8_t bfr = *(const bh8_t*)(gb + (16u * (4u * w + nt) + lr) * 32u + lq * 8u);
        dacc[nt][0] = MFMA16(a0, bfr, dacc[nt][0]);
        dacc[nt][1] = MFMA16(a1, bfr, dacc[nt][1]);
      }
    }

    // ---- momentum update: dV += min(V,0)*2/512; d = .9d - .01dV; V += d ----
#pragma unroll
    for (int nt = 0; nt < 4; ++nt)
#pragma unroll
      for (int mt = 0; mt < 2; ++mt) {
        float dv0 = dacc[nt][mt][0] + fminf(Vreg[mt][nt][0], 0.f) * 0.00390625f;
        float dv1 = dacc[nt][mt][1] + fminf(Vreg[mt][nt][1], 0.f) * 0.00390625f;
        float dv2 = dacc[nt][mt][2] + fminf(Vreg[mt][nt][2], 0.f) * 0.00390625f;
        float dv3 = dacc[nt][mt][3] + fminf(Vreg[mt][nt][3], 0.f) * 0.00390625f;
        float d0 = 0.9f * up_lo(Dpk[mt][nt][0]) - 0.01f * dv0;
        float d1 = 0.9f * up_hi(Dpk[mt][nt][0]) - 0.01f * dv1;
        float d2 = 0.9f * up_lo(Dpk[mt][nt][1]) - 0.01f * dv2;
        float d3 = 0.9f * up_hi(Dpk[mt][nt][1]) - 0.01f * dv3;
        Vreg[mt][nt][0] += d0; Vreg[mt][nt][1] += d1;
        Vreg[mt][nt][2] += d2; Vreg[mt][nt][3] += d3;
        Dpk[mt][nt][0] = pk2(d0, d1);
        Dpk[mt][nt][1] = pk2(d2, d3);
      }
  }

  // ---- write final V ----
#pragma unroll
  for (int mt = 0; mt < 2; ++mt)
#pragma unroll
    for (int n = 0; n < 4; ++n) {
      unsigned col = 16u * (4u * w + n) + lr;
#pragma unroll
      for (int r = 0; r < 4; ++r)
        out[(row0 + 16u * mt + 4u * lq + r) * 512u + col] = Vreg[mt][n][r];
    }
}

extern "C" void kernel_launch(void* const* d_in, const int* in_sizes, int n_in,
                              void* d_out, int out_size, void* d_ws, size_t ws_size,
                              hipStream_t stream) {
  const float* input = (const float*)d_in[0];
  // d_in[1] = Vref (unused by reference)
  const float* Vin = (const float*)d_in[2];
  const float* W1  = (const float*)d_in[3];
  const float* b1  = (const float*)d_in[4];
  const float* W2  = (const float*)d_in[5];
  const float* b2  = (const float*)d_in[6];
  const float* S   = (const float*)d_in[7];
  const float* Pin = (const float*)d_in[8];
  const int* nit   = (const int*)d_in[9];
  bhalf* ws  = (bhalf*)d_ws;
  float* out = (float*)d_out;

  amn_prep<<<3072, 256, 0, stream>>>(W1, W2, Pin, ws);
  amn_gram<<<1024, 256, 0, stream>>>(S, ws);
  amn_main<<<1024, 512, 0, stream>>>(input, Vin, b1, b2, nit, ws, out);
}